// Round 1
// baseline (1074.800 us; speedup 1.0000x reference)
//
#include <hip/hip_runtime.h>

// SNN event model: causal conv1d (K=16) + leaky integrate-and-fire scan + logits.
// Strategy: chunk the time axis (16 chunks x 512) with a 256-step warm-up from
// v=0 (contraction factor 0.8/step -> bitwise-converged state at chunk start
// w.h.p.; spikes reset state exactly). Block = one (b, chunk), thread = filter.
// LDS tile transpose for fully coalesced float4 output writes.

namespace {
constexpr int Bn = 64;
constexpr int Fn = 128;
constexpr int Ln = 8192;
constexpr int Kn = 16;
constexpr int CHUNK = 512;
constexpr int LOOK  = 256;
constexpr int TILE  = 32;
constexpr int NTILE = CHUNK / TILE;      // 16
constexpr int TS    = 33;                // LDS tile row stride (f-major), odd -> <=2-way banks
constexpr int XBUF  = LOOK + CHUNK + Kn; // 784 floats of x staged per block
constexpr float KDT = 0.2f;              // DT/TAU
}

__global__ __launch_bounds__(128)
void snn_fused(const float* __restrict__ x, const float* __restrict__ W,
               const float* __restrict__ bias, float* __restrict__ out)
{
    __shared__ float xs[XBUF];
    __shared__ float tI[Fn * TS];
    __shared__ float tV[Fn * TS];
    __shared__ float red[4 * TILE];

    const int tid   = threadIdx.x;      // 0..127 == filter f
    const int f     = tid;
    const int chunk = blockIdx.x;       // 0..15
    const int b     = blockIdx.y;       // 0..63
    const int t0    = chunk * CHUNK;
    const int warm  = chunk ? LOOK : 0;
    const int tstart = t0 - warm;       // multiple of 16
    const int xlo    = tstart - (Kn - 1);

    // ---- stage x[b, xlo .. xlo+XBUF) into LDS (zero for t<0 causal pad) ----
    const float* xrow = x + (size_t)b * Ln;
    for (int i = tid; i < XBUF; i += Fn) {
        int g = xlo + i;
        xs[i] = (g >= 0 && g < Ln) ? xrow[g] : 0.0f;
    }

    float w[Kn];
#pragma unroll
    for (int k = 0; k < Kn; ++k) w[k] = W[f * Kn + k];
    const float bf = bias[f];

    __syncthreads();

    // rotating 16-float window: slot (g & 15) holds x[g]
    float xw[16];
#pragma unroll
    for (int i = 1; i < 16; ++i) xw[i] = xs[i - 1];  // x[tstart-16+i], slot i
    xw[0] = 0.0f;                                     // overwritten at first step

    float v = 0.0f;

    const size_t OO = (size_t)Bn * Fn * Ln;
    float* outI  = out;
    float* outVP = out + OO;
    float* outV  = out + 2 * OO;
    float* outS  = out + 3 * OO;
    float* outLG = out + 4 * OO;

    // ---- warm-up: 256 steps (0 for chunk 0), no stores ----
    for (int t = tstart; t < t0; t += 16) {
        int base = t - xlo;
#pragma unroll
        for (int j = 0; j < 16; ++j) {        // j == (t+j) & 15  (t % 16 == 0)
            float xn = xs[base + j];
            xw[j] = xn;
            float acc = 0.0f;
#pragma unroll
            for (int k = 0; k < Kn; ++k)
                acc = fmaf(w[k], xw[(j + 1 + k) & 15], acc);
            float I  = __fadd_rn(acc, bf);
            float pr = __fmul_rn(KDT, __fsub_rn(I, v));
            float vp = __fadd_rn(v, pr);
            v = (vp >= 1.0f) ? 0.0f : vp;
        }
    }

    // ---- main: 16 tiles of 32 steps, LDS transpose, coalesced writes ----
    const int fTS = f * TS;
    for (int tile = 0; tile < NTILE; ++tile) {
        const int tb   = t0 + tile * TILE;
        const int base = tb - xlo;
#pragma unroll
        for (int u = 0; u < TILE; ++u) {
            const int j = u & 15;             // == (tb+u) & 15
            float xn = xs[base + u];
            xw[j] = xn;
            float acc = 0.0f;
#pragma unroll
            for (int k = 0; k < Kn; ++k)
                acc = fmaf(w[k], xw[(j + 1 + k) & 15], acc);
            float I  = __fadd_rn(acc, bf);
            float pr = __fmul_rn(KDT, __fsub_rn(I, v));
            float vp = __fadd_rn(v, pr);
            tI[fTS + u] = I;
            tV[fTS + u] = vp;
            v = (vp >= 1.0f) ? 0.0f : vp;     // exact: vp*(1-s)
        }
        __syncthreads();

        // coalesced global writes: wave = 8 f-rows x 128B contiguous segments
#pragma unroll
        for (int grp = 0; grp < 8; ++grp) {
            int g2 = grp * Fn + tid;          // 0..1023 (4-elem groups)
            int fr = g2 >> 3;
            int t4 = (g2 & 7) * 4;
            size_t gaddr = ((size_t)b * Fn + fr) * Ln + (size_t)(tb + t4);
            int la = fr * TS + t4;

            float4 vi = make_float4(tI[la], tI[la + 1], tI[la + 2], tI[la + 3]);
            *(float4*)(outI + gaddr) = vi;

            float a0 = tV[la], a1 = tV[la + 1], a2 = tV[la + 2], a3 = tV[la + 3];
            *(float4*)(outVP + gaddr) = make_float4(a0, a1, a2, a3);
            *(float4*)(outV + gaddr) = make_float4(
                (a0 >= 1.0f) ? 0.0f : a0, (a1 >= 1.0f) ? 0.0f : a1,
                (a2 >= 1.0f) ? 0.0f : a2, (a3 >= 1.0f) ? 0.0f : a3);
            *(float4*)(outS + gaddr) = make_float4(
                (a0 >= 1.0f) ? 1.0f : 0.0f, (a1 >= 1.0f) ? 1.0f : 0.0f,
                (a2 >= 1.0f) ? 1.0f : 0.0f, (a3 >= 1.0f) ? 1.0f : 0.0f);
        }

        // logits partial: max over 32 filters per (fgroup, t)
        {
            int fg = tid >> 5, tt = tid & 31;
            float m = -3.402823466e38f;
#pragma unroll
            for (int i = 0; i < 32; ++i)
                m = fmaxf(m, tV[(fg * 32 + i) * TS + tt]);
            red[fg * 32 + tt] = m;
        }
        __syncthreads();
        if (tid < 32) {
            float m = fmaxf(fmaxf(red[tid], red[32 + tid]),
                            fmaxf(red[64 + tid], red[96 + tid]));
            outLG[(size_t)b * Ln + (size_t)(tb + tid)] = __fsub_rn(m, 1.0f);
        }
        // next tile's first __syncthreads-free phase only writes tI/tV, whose
        // readers all finished before the barrier above; red is read only by
        // tid<32 before they reach the next barrier.
    }
}

extern "C" void kernel_launch(void* const* d_in, const int* in_sizes, int n_in,
                              void* d_out, int out_size, void* d_ws, size_t ws_size,
                              hipStream_t stream) {
    const float* x = (const float*)d_in[0];
    const float* W = (const float*)d_in[1];
    const float* b = (const float*)d_in[2];
    float* out = (float*)d_out;
    dim3 grid(16, 64);   // (chunk, batch) -> 1024 blocks, 4 per CU resident
    snn_fused<<<grid, 128, 0, stream>>>(x, W, b, out);
}